// Round 1
// 5115.661 us; speedup vs baseline: 3.0499x; 3.0499x over previous
//
#include <hip/hip_runtime.h>
#include <hip/hip_bf16.h>

#define TDIM 1024
#define HDIM 1024
#define IDIM 1024
#define BSZ  64

typedef __attribute__((ext_vector_type(4))) float  floatx4;
typedef __attribute__((ext_vector_type(8))) short  shortx8;

static __device__ __forceinline__ short f2bf(float x) {
    unsigned u = __builtin_bit_cast(unsigned, x);
    u += 0x7fffu + ((u >> 16) & 1u);           // round-to-nearest-even
    return (short)(u >> 16);
}

static __device__ __forceinline__ shortx8 pack8(floatx4 a, floatx4 b) {
    shortx8 r;
    r[0] = f2bf(a[0]); r[1] = f2bf(a[1]); r[2] = f2bf(a[2]); r[3] = f2bf(a[3]);
    r[4] = f2bf(b[0]); r[5] = f2bf(b[1]); r[6] = f2bf(b[2]); r[7] = f2bf(b[3]);
    return r;
}

// ---------------------------------------------------------------------------
// Phase A: out[m][n] = sum_k input[m][k] * W_ih[n][k] + b_ih[n] + b_hh[n]
// (unchanged from previous round — ~0.75 ms, not the lever this round)
// ---------------------------------------------------------------------------
__global__ __launch_bounds__(256, 2)
void xp_gemm(const float* __restrict__ A, const float* __restrict__ W,
             const float* __restrict__ bih, const float* __restrict__ bhh,
             float* __restrict__ out)
{
    __shared__ short As[128 * 72];
    __shared__ short Bs[128 * 72];

    const int tid  = threadIdx.x;
    const int bx   = blockIdx.x;
    const int m0   = (bx >> 3) * 128;
    const int n0   = (bx & 7) * 128;
    const int lane = tid & 63;
    const int w    = tid >> 6;
    const int wm   = w & 1, wn = w >> 1;
    const int col  = lane & 15, quad = lane >> 4;

    const int srow = tid >> 1;
    const int scol = (tid & 1) * 32;
    const float* ap = A + (size_t)(m0 + srow) * IDIM + scol;
    const float* wp = W + (size_t)(n0 + srow) * IDIM + scol;
    short* asw = As + srow * 72 + scol;
    short* bsw = Bs + srow * 72 + scol;

    floatx4 acc[4][4];
#pragma unroll
    for (int i = 0; i < 4; i++)
#pragma unroll
        for (int j = 0; j < 4; j++) acc[i][j] = (floatx4){0.f, 0.f, 0.f, 0.f};

    for (int kt = 0; kt < IDIM; kt += 64) {
        floatx4 av[8], bv[8];
        const floatx4* pa = (const floatx4*)(ap + kt);
        const floatx4* pb = (const floatx4*)(wp + kt);
#pragma unroll
        for (int q = 0; q < 8; q++) { av[q] = pa[q]; bv[q] = pb[q]; }
        __syncthreads();
#pragma unroll
        for (int q = 0; q < 4; q++) {
            *(shortx8*)(asw + q * 8) = pack8(av[2 * q], av[2 * q + 1]);
            *(shortx8*)(bsw + q * 8) = pack8(bv[2 * q], bv[2 * q + 1]);
        }
        __syncthreads();
#pragma unroll
        for (int kb = 0; kb < 64; kb += 32) {
            shortx8 af[4], bf[4];
#pragma unroll
            for (int i = 0; i < 4; i++)
                af[i] = *(const shortx8*)(As + (wm * 64 + i * 16 + col) * 72 + kb + quad * 8);
#pragma unroll
            for (int j = 0; j < 4; j++)
                bf[j] = *(const shortx8*)(Bs + (wn * 64 + j * 16 + col) * 72 + kb + quad * 8);
#pragma unroll
            for (int i = 0; i < 4; i++)
#pragma unroll
                for (int j = 0; j < 4; j++)
                    acc[i][j] = __builtin_amdgcn_mfma_f32_16x16x32_bf16(af[i], bf[j], acc[i][j], 0, 0, 0);
        }
    }

#pragma unroll
    for (int j = 0; j < 4; j++) {
        const int n = n0 + wn * 64 + j * 16 + col;
        const float bias = bih[n] + bhh[n];
#pragma unroll
        for (int i = 0; i < 4; i++) {
            const int mb = m0 + wm * 64 + i * 16 + quad * 4;
#pragma unroll
            for (int r = 0; r < 4; r++)
                out[(size_t)(mb + r) * HDIM + n] = acc[i][j][r] + bias;
        }
    }
}

// ---------------------------------------------------------------------------
// Phase B: recurrence. 32 WGs of 512 threads = 4 batch-groups (gm, 16 batches)
// x 8 n-WGs (gn, 128 neurons; 8 waves x 16 neurons).  W_hh in registers
// (128 VGPR/thread).  Per-group counter barrier per step.
//
// Coherence design (replaces __threadfence):
//   - h exchange (hbuf) and counters use agent-scope atomics only -> sc1,
//     write-through to MALL / loads from MALL.  No L2 state to flush.
//   - release = s_waitcnt vmcnt(0) before the counter RMW (store-ack at MALL)
//   - acquire = nothing (sc1 loads cannot hit a stale cache); compiler
//     clobber after the spin prevents hoisting.
//   - out[] is WG-private (same WG reads x_proj / writes h at same index):
//     no coherence needed; nontemporal to keep it out of L2.
// ---------------------------------------------------------------------------
__global__ __launch_bounds__(512, 1)
void rnn_rec(float* __restrict__ out,          // in: x_proj (fp32); overwritten with h
             const float* __restrict__ Whh, const float* __restrict__ h0,
             float* __restrict__ hbuf, unsigned* __restrict__ cnt)
{
    __shared__ short hlds[16 * 1032];   // 16 batches x 1024 k, pitch 1032

    const int tid  = threadIdx.x;
    const int gm   = blockIdx.x >> 3;   // 0..3
    const int gn   = blockIdx.x & 7;    // 0..7
    const int lane = tid & 63;
    const int w    = tid >> 6;          // 0..7
    const int col  = lane & 15, quad = lane >> 4;
    const int nglob = gn * 128 + w * 16 + col;
    unsigned* mycnt = cnt + gm * 32;    // 128 B apart

    // B-fragments: W_hh[n][k], k = kb*32 + quad*8 + j  (j = 0..7)
    shortx8 bfrag[32];
    {
        const float* wrow = Whh + (size_t)nglob * HDIM + quad * 8;
#pragma unroll
        for (int kb = 0; kb < 32; kb++) {
            const floatx4* p = (const floatx4*)(wrow + kb * 32);
            bfrag[kb] = pack8(p[0], p[1]);
        }
    }

    const size_t slice = (size_t)gm * 16 * HDIM;
    const int b0 = gm * 16 + quad * 4;

    // prefetch x_proj for t = 0
    float xp[4];
#pragma unroll
    for (int r = 0; r < 4; r++)
        xp[r] = __builtin_nontemporal_load(out + (size_t)(b0 + r) * (TDIM * HDIM) + nglob);

    for (int t = 0; t < TDIM; ++t) {
        // ---- stage h (sc1 loads from MALL) -> LDS bf16 ----
        const float* src = (t == 0) ? (h0 + slice)
                                    : (hbuf + (size_t)(t & 1) * (BSZ * HDIM) + slice);
        const unsigned long long* s8 = (const unsigned long long*)src;
        unsigned long long hv[16];
#pragma unroll
        for (int j = 0; j < 16; j++)
            hv[j] = __hip_atomic_load(s8 + j * 512 + tid, __ATOMIC_RELAXED, __HIP_MEMORY_SCOPE_AGENT);
#pragma unroll
        for (int j = 0; j < 16; j++) {
            const int e = (j * 512 + tid) * 2;
            const int m = e >> 10, k = e & 1023;
            float2 f = __builtin_bit_cast(float2, hv[j]);
            const int packed = ((int)(unsigned short)f2bf(f.x)) |
                               (((int)(unsigned short)f2bf(f.y)) << 16);
            *(int*)(hlds + m * 1032 + k) = packed;
        }
        __syncthreads();

        // ---- prefetch next step's x_proj (hides HBM latency under MFMA) ----
        float xpn[4];
        if (t + 1 < TDIM) {
#pragma unroll
            for (int r = 0; r < 4; r++)
                xpn[r] = __builtin_nontemporal_load(
                    out + (size_t)(b0 + r) * (TDIM * HDIM) + (size_t)(t + 1) * HDIM + nglob);
        }

        // ---- K loop: 32 MFMAs in 4 independent accumulate chains ----
        floatx4 a0 = (floatx4){0.f, 0.f, 0.f, 0.f};
        floatx4 a1 = a0, a2 = a0, a3 = a0;
#pragma unroll
        for (int kb = 0; kb < 32; kb += 4) {
            shortx8 f0 = *(const shortx8*)(hlds + col * 1032 + (kb + 0) * 32 + quad * 8);
            shortx8 f1 = *(const shortx8*)(hlds + col * 1032 + (kb + 1) * 32 + quad * 8);
            shortx8 f2 = *(const shortx8*)(hlds + col * 1032 + (kb + 2) * 32 + quad * 8);
            shortx8 f3 = *(const shortx8*)(hlds + col * 1032 + (kb + 3) * 32 + quad * 8);
            a0 = __builtin_amdgcn_mfma_f32_16x16x32_bf16(f0, bfrag[kb + 0], a0, 0, 0, 0);
            a1 = __builtin_amdgcn_mfma_f32_16x16x32_bf16(f1, bfrag[kb + 1], a1, 0, 0, 0);
            a2 = __builtin_amdgcn_mfma_f32_16x16x32_bf16(f2, bfrag[kb + 2], a2, 0, 0, 0);
            a3 = __builtin_amdgcn_mfma_f32_16x16x32_bf16(f3, bfrag[kb + 3], a3, 0, 0, 0);
        }
        floatx4 acc = (a0 + a1) + (a2 + a3);

        // ---- epilogue: tanh, write out (nt) + next-h (sc1) ----
        float* hout = hbuf + (size_t)((t + 1) & 1) * (BSZ * HDIM);
#pragma unroll
        for (int r = 0; r < 4; r++) {
            const int b = b0 + r;
            const size_t oidx = (size_t)b * (TDIM * HDIM) + (size_t)t * HDIM + nglob;
            const float h = tanhf(xp[r] + acc[r]);
            __builtin_nontemporal_store(h, out + oidx);
            __hip_atomic_store(hout + (size_t)b * HDIM + nglob, h,
                               __ATOMIC_RELAXED, __HIP_MEMORY_SCOPE_AGENT);
            if (t == TDIM - 1)
                out[(size_t)BSZ * TDIM * HDIM + (size_t)b * HDIM + nglob] = h;
        }
#pragma unroll
        for (int r = 0; r < 4; r++) xp[r] = xpn[r];

        // ---- group barrier (8 WGs sharing gm), no L2 flush ----
        if (t + 1 < TDIM) {
            asm volatile("s_waitcnt vmcnt(0)" ::: "memory");  // h stores acked at MALL
            __syncthreads();                                  // all waves drained
            if (tid == 0) {
                __hip_atomic_fetch_add(mycnt, 1u, __ATOMIC_RELAXED, __HIP_MEMORY_SCOPE_AGENT);
                const unsigned target = 8u * (unsigned)(t + 1);
                int guard = 0;
                while (__hip_atomic_load(mycnt, __ATOMIC_RELAXED, __HIP_MEMORY_SCOPE_AGENT) < target) {
                    if (++guard > (1 << 20)) break;   // hang fuse
                }
            }
            __syncthreads();
            asm volatile("" ::: "memory");            // no hoisting loads above spin
        }
    }
}

// ---------------------------------------------------------------------------
extern "C" void kernel_launch(void* const* d_in, const int* in_sizes, int n_in,
                              void* d_out, int out_size, void* d_ws, size_t ws_size,
                              hipStream_t stream)
{
    const float* input = (const float*)d_in[0];
    const float* h0    = (const float*)d_in[1];
    const float* W_ih  = (const float*)d_in[2];
    const float* b_ih  = (const float*)d_in[3];
    const float* W_hh  = (const float*)d_in[4];
    const float* b_hh  = (const float*)d_in[5];
    float* out = (float*)d_out;

    char* ws = (char*)d_ws;
    float*    hbuf = (float*)ws;                                   // 512 KiB ping-pong
    unsigned* cnt  = (unsigned*)(ws + (size_t)2 * BSZ * HDIM * 4); // 512 B counters

    hipMemsetAsync(cnt, 0, 512, stream);

    xp_gemm<<<dim3(4096), dim3(256), 0, stream>>>(input, W_ih, b_ih, b_hh, out);
    rnn_rec<<<dim3(32),   dim3(512), 0, stream>>>(out, W_hh, h0, hbuf, cnt);
}

// Round 2
// 4932.537 us; speedup vs baseline: 3.1632x; 1.0371x over previous
//
#include <hip/hip_runtime.h>
#include <hip/hip_bf16.h>

#define TDIM 1024
#define HDIM 1024
#define IDIM 1024
#define BSZ  64

typedef __attribute__((ext_vector_type(4))) float  floatx4;
typedef __attribute__((ext_vector_type(8))) short  shortx8;

static __device__ __forceinline__ short f2bf(float x) {
    unsigned u = __builtin_bit_cast(unsigned, x);
    u += 0x7fffu + ((u >> 16) & 1u);           // round-to-nearest-even
    return (short)(u >> 16);
}

static __device__ __forceinline__ shortx8 pack8(floatx4 a, floatx4 b) {
    shortx8 r;
    r[0] = f2bf(a[0]); r[1] = f2bf(a[1]); r[2] = f2bf(a[2]); r[3] = f2bf(a[3]);
    r[4] = f2bf(b[0]); r[5] = f2bf(b[1]); r[6] = f2bf(b[2]); r[7] = f2bf(b[3]);
    return r;
}

// ---------------------------------------------------------------------------
// Phase A: out[m][n] = sum_k input[m][k] * W_ih[n][k] + b_ih[n] + b_hh[n]
// (unchanged — ~0.75 ms)
// ---------------------------------------------------------------------------
__global__ __launch_bounds__(256, 2)
void xp_gemm(const float* __restrict__ A, const float* __restrict__ W,
             const float* __restrict__ bih, const float* __restrict__ bhh,
             float* __restrict__ out)
{
    __shared__ short As[128 * 72];
    __shared__ short Bs[128 * 72];

    const int tid  = threadIdx.x;
    const int bx   = blockIdx.x;
    const int m0   = (bx >> 3) * 128;
    const int n0   = (bx & 7) * 128;
    const int lane = tid & 63;
    const int w    = tid >> 6;
    const int wm   = w & 1, wn = w >> 1;
    const int col  = lane & 15, quad = lane >> 4;

    const int srow = tid >> 1;
    const int scol = (tid & 1) * 32;
    const float* ap = A + (size_t)(m0 + srow) * IDIM + scol;
    const float* wp = W + (size_t)(n0 + srow) * IDIM + scol;
    short* asw = As + srow * 72 + scol;
    short* bsw = Bs + srow * 72 + scol;

    floatx4 acc[4][4];
#pragma unroll
    for (int i = 0; i < 4; i++)
#pragma unroll
        for (int j = 0; j < 4; j++) acc[i][j] = (floatx4){0.f, 0.f, 0.f, 0.f};

    for (int kt = 0; kt < IDIM; kt += 64) {
        floatx4 av[8], bv[8];
        const floatx4* pa = (const floatx4*)(ap + kt);
        const floatx4* pb = (const floatx4*)(wp + kt);
#pragma unroll
        for (int q = 0; q < 8; q++) { av[q] = pa[q]; bv[q] = pb[q]; }
        __syncthreads();
#pragma unroll
        for (int q = 0; q < 4; q++) {
            *(shortx8*)(asw + q * 8) = pack8(av[2 * q], av[2 * q + 1]);
            *(shortx8*)(bsw + q * 8) = pack8(bv[2 * q], bv[2 * q + 1]);
        }
        __syncthreads();
#pragma unroll
        for (int kb = 0; kb < 64; kb += 32) {
            shortx8 af[4], bf[4];
#pragma unroll
            for (int i = 0; i < 4; i++)
                af[i] = *(const shortx8*)(As + (wm * 64 + i * 16 + col) * 72 + kb + quad * 8);
#pragma unroll
            for (int j = 0; j < 4; j++)
                bf[j] = *(const shortx8*)(Bs + (wn * 64 + j * 16 + col) * 72 + kb + quad * 8);
#pragma unroll
            for (int i = 0; i < 4; i++)
#pragma unroll
                for (int j = 0; j < 4; j++)
                    acc[i][j] = __builtin_amdgcn_mfma_f32_16x16x32_bf16(af[i], bf[j], acc[i][j], 0, 0, 0);
        }
    }

#pragma unroll
    for (int j = 0; j < 4; j++) {
        const int n = n0 + wn * 64 + j * 16 + col;
        const float bias = bih[n] + bhh[n];
#pragma unroll
        for (int i = 0; i < 4; i++) {
            const int mb = m0 + wm * 64 + i * 16 + quad * 4;
#pragma unroll
            for (int r = 0; r < 4; r++)
                out[(size_t)(mb + r) * HDIM + n] = acc[i][j][r] + bias;
        }
    }
}

// ---------------------------------------------------------------------------
// Phase B: recurrence. 32 WGs of 512 threads = 4 batch-groups (gm, 16 batches)
// x 8 n-WGs (gn, 128 neurons; 8 waves x 16 neurons).  W_hh in registers.
//
// Sync design (replaces the counter barrier):
//   - per-producer epoch FLAGS: WG (gm,gn) sets flag[gm][gn] = t+1 after its
//     h stores are acked at MALL (s_waitcnt vmcnt(0) + __syncthreads).
//     No atomic RMW anywhere; no global join.
//   - staging thread tid stages h[m][2*tid .. 2*tid+1]; its k-slice belongs
//     to exactly one producer (k/128 == wave id w).  So wave w polls ONLY
//     flag[gm][w] and starts staging the moment that producer finishes —
//     producer skew overlaps with staging instead of stacking on a barrier.
//   - hlds overwrite hazard: staging(t+1) happens after the epilogue's
//     __syncthreads (all waves' MFMA reads of step t done).
//   - out[] nt-stores are WG-private: issued AFTER the flag (off the
//     critical release path); their drain folds into the next step's slack.
//   - ping-pong hbuf gives 2-step write/read separation: producer cannot
//     reach epilogue(t+2) until every group member set flag >= t+2.
// ---------------------------------------------------------------------------
__global__ __launch_bounds__(512, 1)
void rnn_rec(float* __restrict__ out,          // in: x_proj (fp32); overwritten with h
             const float* __restrict__ Whh, const float* __restrict__ h0,
             float* __restrict__ hbuf, unsigned* __restrict__ cnt)
{
    __shared__ short hlds[16 * 1032];   // 16 batches x 1024 k, pitch 1032

    const int tid  = threadIdx.x;
    const int gm   = blockIdx.x >> 3;   // 0..3
    const int gn   = blockIdx.x & 7;    // 0..7
    const int lane = tid & 63;
    const int w    = tid >> 6;          // 0..7
    const int col  = lane & 15, quad = lane >> 4;
    const int nglob = gn * 128 + w * 16 + col;

    // flags: 128 B apart; wave w consumes producer w's slice (k = 128w..128w+127)
    unsigned* myflag = cnt + (size_t)(gm * 8 + w)  * 32;   // polled by wave w
    unsigned* pflag  = cnt + (size_t)(gm * 8 + gn) * 32;   // set by this WG

    // B-fragments: W_hh[n][k], k = kb*32 + quad*8 + j  (j = 0..7)
    shortx8 bfrag[32];
    {
        const float* wrow = Whh + (size_t)nglob * HDIM + quad * 8;
#pragma unroll
        for (int kb = 0; kb < 32; kb++) {
            const floatx4* p = (const floatx4*)(wrow + kb * 32);
            bfrag[kb] = pack8(p[0], p[1]);
        }
    }

    const size_t slice = (size_t)gm * 16 * HDIM;
    const int b0 = gm * 16 + quad * 4;
    const int k2 = tid * 2;              // this thread's k pair (0..1022)

    // prefetch x_proj for t = 0
    float xp[4];
#pragma unroll
    for (int r = 0; r < 4; r++)
        xp[r] = __builtin_nontemporal_load(out + (size_t)(b0 + r) * (TDIM * HDIM) + nglob);

    for (int t = 0; t < TDIM; ++t) {
        // ---- wait for MY producer only (wave-uniform poll, no RMW) ----
        if (t > 0) {
            if (lane == 0) {
                const unsigned target = (unsigned)t;
                int guard = 0;
                while (__hip_atomic_load(myflag, __ATOMIC_RELAXED, __HIP_MEMORY_SCOPE_AGENT) < target) {
                    if (++guard > (1 << 22)) break;   // hang fuse
                }
            }
            // lanes reconverge behind lane0's loop; block load hoisting
            asm volatile("" ::: "memory");
        }

        // ---- stage h (sc1 loads from MALL) -> LDS bf16 ----
        const float* src = (t == 0) ? (h0 + slice)
                                    : (hbuf + (size_t)(t & 1) * (BSZ * HDIM) + slice);
        const unsigned long long* s8 = (const unsigned long long*)src;
        unsigned long long hv[16];
#pragma unroll
        for (int j = 0; j < 16; j++)
            hv[j] = __hip_atomic_load(s8 + (size_t)j * 512 + tid, __ATOMIC_RELAXED, __HIP_MEMORY_SCOPE_AGENT);
#pragma unroll
        for (int j = 0; j < 16; j++) {
            float2 f = __builtin_bit_cast(float2, hv[j]);
            const int packed = ((int)(unsigned short)f2bf(f.x)) |
                               (((int)(unsigned short)f2bf(f.y)) << 16);
            *(int*)(hlds + j * 1032 + k2) = packed;
        }
        __syncthreads();                 // all 8 k-slices staged

        // ---- prefetch next step's x_proj (covered by MFMA + next barrier) ----
        float xpn[4];
        if (t + 1 < TDIM) {
#pragma unroll
            for (int r = 0; r < 4; r++)
                xpn[r] = __builtin_nontemporal_load(
                    out + (size_t)(b0 + r) * (TDIM * HDIM) + (size_t)(t + 1) * HDIM + nglob);
        }

        // ---- K loop: 32 MFMAs in 4 independent accumulate chains ----
        floatx4 a0 = (floatx4){0.f, 0.f, 0.f, 0.f};
        floatx4 a1 = a0, a2 = a0, a3 = a0;
#pragma unroll
        for (int kb = 0; kb < 32; kb += 4) {
            shortx8 f0 = *(const shortx8*)(hlds + col * 1032 + (kb + 0) * 32 + quad * 8);
            shortx8 f1 = *(const shortx8*)(hlds + col * 1032 + (kb + 1) * 32 + quad * 8);
            shortx8 f2 = *(const shortx8*)(hlds + col * 1032 + (kb + 2) * 32 + quad * 8);
            shortx8 f3 = *(const shortx8*)(hlds + col * 1032 + (kb + 3) * 32 + quad * 8);
            a0 = __builtin_amdgcn_mfma_f32_16x16x32_bf16(f0, bfrag[kb + 0], a0, 0, 0, 0);
            a1 = __builtin_amdgcn_mfma_f32_16x16x32_bf16(f1, bfrag[kb + 1], a1, 0, 0, 0);
            a2 = __builtin_amdgcn_mfma_f32_16x16x32_bf16(f2, bfrag[kb + 2], a2, 0, 0, 0);
            a3 = __builtin_amdgcn_mfma_f32_16x16x32_bf16(f3, bfrag[kb + 3], a3, 0, 0, 0);
        }
        floatx4 acc = (a0 + a1) + (a2 + a3);

        // ---- epilogue: tanh, release h FIRST, out[] stores after the flag ----
        float* hout = hbuf + (size_t)((t + 1) & 1) * (BSZ * HDIM);
        float hval[4];
#pragma unroll
        for (int r = 0; r < 4; r++)
            hval[r] = tanhf(xp[r] + acc[r]);
#pragma unroll
        for (int r = 0; r < 4; r++)
            __hip_atomic_store(hout + (size_t)(b0 + r) * HDIM + nglob, hval[r],
                               __ATOMIC_RELAXED, __HIP_MEMORY_SCOPE_AGENT);

        asm volatile("s_waitcnt vmcnt(0)" ::: "memory");  // h acked at MALL (per wave)
        __syncthreads();                                  // all waves acked + MFMA reads done
        if (tid == 0)
            __hip_atomic_store(pflag, (unsigned)(t + 1),
                               __ATOMIC_RELAXED, __HIP_MEMORY_SCOPE_AGENT);

        // WG-private writes — off the release path
#pragma unroll
        for (int r = 0; r < 4; r++) {
            const int b = b0 + r;
            const size_t oidx = (size_t)b * (TDIM * HDIM) + (size_t)t * HDIM + nglob;
            __builtin_nontemporal_store(hval[r], out + oidx);
            if (t == TDIM - 1)
                out[(size_t)BSZ * TDIM * HDIM + (size_t)b * HDIM + nglob] = hval[r];
        }
#pragma unroll
        for (int r = 0; r < 4; r++) xp[r] = xpn[r];
    }
}

// ---------------------------------------------------------------------------
extern "C" void kernel_launch(void* const* d_in, const int* in_sizes, int n_in,
                              void* d_out, int out_size, void* d_ws, size_t ws_size,
                              hipStream_t stream)
{
    const float* input = (const float*)d_in[0];
    const float* h0    = (const float*)d_in[1];
    const float* W_ih  = (const float*)d_in[2];
    const float* b_ih  = (const float*)d_in[3];
    const float* W_hh  = (const float*)d_in[4];
    const float* b_hh  = (const float*)d_in[5];
    float* out = (float*)d_out;

    char* ws = (char*)d_ws;
    float*    hbuf = (float*)ws;                                   // 512 KiB ping-pong
    unsigned* cnt  = (unsigned*)(ws + (size_t)2 * BSZ * HDIM * 4); // 4 KiB flags

    hipMemsetAsync(cnt, 0, 4096, stream);

    xp_gemm<<<dim3(4096), dim3(256), 0, stream>>>(input, W_ih, b_ih, b_hh, out);
    rnn_rec<<<dim3(32),   dim3(512), 0, stream>>>(out, W_hh, h0, hbuf, cnt);
}